// Round 12
// baseline (121.797 us; speedup 1.0000x reference)
//
#include <hip/hip_runtime.h>
#include <math.h>
#include <stdint.h>

#define GAMMA 0.7f
#define TCAP 1024   // per-tile bucket capacity (mean ~583)
#define RQCAP 96    // per-row queue capacity (mean ~37)

typedef __attribute__((ext_vector_type(8))) short short8v;   // 8 bf16
typedef __attribute__((ext_vector_type(4))) float f32x4;

__device__ __forceinline__ float sp_dev(float x) {
    return fmaxf(x, 0.0f) + log1pf(expf(-fabsf(x)));
}
__device__ __forceinline__ float gelu_exact(float x) {
    return 0.5f * x * (1.0f + erff(x * 0.70710678118654752f));
}
__device__ __forceinline__ uint16_t f2bf(float x) {
    union { float f; uint32_t u; } c; c.f = x;
    uint32_t u = c.u + 0x7FFFu + ((c.u >> 16) & 1u);
    return (uint16_t)(u >> 16);
}

// ===========================================================================
// K0: zero tile counters + walk coefficients + bf16 transposed weights
// ===========================================================================
__global__ __launch_bounds__(256) void k0_kernel(
    const float* __restrict__ Wt0, const float* __restrict__ Wc0, const float* __restrict__ g0,
    const float* __restrict__ Wt1, const float* __restrict__ Wc1, const float* __restrict__ g1,
    const float* __restrict__ w1_0, const float* __restrict__ w2_0,
    const float* __restrict__ w1_1, const float* __restrict__ w2_1,
    float* __restrict__ dcoef, int* __restrict__ tcnt,
    uint16_t* __restrict__ Wb10, uint16_t* __restrict__ Wb20,
    uint16_t* __restrict__ Wb11, uint16_t* __restrict__ Wb21, int ntiles) {
    int tid = threadIdx.x;
    int gtid = blockIdx.x * 256 + tid;
    int stride = gridDim.x * 256;

    for (int i = gtid; i < ntiles; i += stride) tcnt[i] = 0;

    if (blockIdx.x == 0 && tid < 32) {
        int L = tid >> 4, m = (tid >> 3) & 1, f = tid & 7;
        int k = m ? 4 : 3;
        const float* W = L ? (m ? Wc1 : Wt1) : (m ? Wc0 : Wt0);
        const float* g = L ? g1 : g0;
        float S[4][4], Y[4][4];
        for (int a = 0; a < k; a++)
            for (int b = 0; b < k; b++)
                S[a][b] = sp_dev(W[(f * k + a) * k + b]);
        for (int a = 0; a < k; a++)
            for (int b = 0; b < k; b++)
                Y[a][b] = (a == b) ? 0.0f : 0.5f * (S[a][b] + S[b][a]);
        for (int a = 0; a < k; a++) {
            float rs = 0.0f;
            for (int b = 0; b < k; b++) rs += Y[a][b];
            rs = fmaxf(rs, 1e-12f);
            for (int b = 0; b < k; b++) Y[a][b] /= rs;
        }
        float t1 = 0, t2 = 0, t3 = 0;
        for (int a = 0; a < k; a++) t1 += Y[a][a];
        for (int a = 0; a < k; a++)
            for (int b = 0; b < k; b++) t2 += Y[a][b] * Y[b][a];
        for (int a = 0; a < k; a++)
            for (int b = 0; b < k; b++)
                for (int c = 0; c < k; c++) t3 += Y[a][b] * Y[b][c] * Y[c][a];
        float* d = dcoef + ((L * 2 + m) * 8 + f) * 3;
        d[0] = GAMMA * sp_dev(g[0]) * t1;
        d[1] = GAMMA * GAMMA * sp_dev(g[1]) * t2;
        d[2] = GAMMA * GAMMA * GAMMA * sp_dev(g[2]) * t3;
    }
    for (int idx = gtid; idx < 57344; idx += stride) {
        if (idx < 4096) {
            int c = idx >> 5, kk = idx & 31;
            Wb10[idx] = (kk < 17) ? f2bf(w1_0[kk * 128 + c]) : 0;
        } else if (idx < 20480) {
            int e = idx - 4096; int c = e >> 7, kk = e & 127;
            Wb20[e] = f2bf(w2_0[kk * 128 + c]);
        } else if (idx < 40960) {
            int e = idx - 20480; int c = e / 160, kk = e % 160;
            Wb11[e] = (kk < 145) ? f2bf(w1_1[kk * 128 + c]) : 0;
        } else {
            int e = idx - 40960; int c = e >> 7, kk = e & 127;
            Wb21[e] = f2bf(w2_1[kk * 128 + c]);
        }
    }
}

// ===========================================================================
// K1: [0,BC) contrib (1 thread/instance, symmetric 3/6-load gather, dense
// cont write + tile-bucket push) ; [BC, BC+n) rowsum (1 row/block).
// ===========================================================================
__global__ __launch_bounds__(256) void k1_kernel(
    const float* __restrict__ A, const int* __restrict__ tri, const int* __restrict__ cyc,
    const float* __restrict__ dcoef,
    float* __restrict__ cont, int* __restrict__ tcnt, int* __restrict__ bucket,
    float* __restrict__ H0, float* __restrict__ out,
    int n, int Itri, int Icyc, int BC) {

    const int tid = threadIdx.x;
    const int bid = blockIdx.x;
    const int Itot = Itri + Icyc;

    if (bid < BC) {
        __shared__ float dcs[2][2][8][3];   // [m][L][f][p]
        if (tid < 96) {
            // dcoef layout ((L*2+m)*8+f)*3 + p
            int L = tid / 48, rem = tid % 48, m = rem / 24, r2 = rem % 24;
            dcs[m][L][r2 / 3][r2 % 3] = dcoef[((L * 2 + m) * 8 + r2 / 3) * 3 + r2 % 3];
        }
        __syncthreads();

        int gi = bid * 256 + tid;
        if (gi >= Itot) return;
        bool isTri = gi < Itri;
        int K = isTri ? 3 : 4;
        int m = isTri ? 0 : 1;
        float kinv = isTri ? (1.0f / 3.0f) : 0.25f;
        const int* p = isTri ? tri + gi * 3 : cyc + (size_t)(gi - Itri) * 4;
        int nd[4];
        nd[0] = p[0]; nd[1] = p[1]; nd[2] = p[2]; nd[3] = isTri ? 0 : p[3];

        // hollow-symmetric submatrix: only upper off-diagonal loads
        float u01 = A[(size_t)nd[0] * n + nd[1]];
        float u02 = A[(size_t)nd[0] * n + nd[2]];
        float u12 = A[(size_t)nd[1] * n + nd[2]];
        float u03 = 0.0f, u13 = 0.0f, u23 = 0.0f, d33 = 1.0f;
        if (!isTri) {
            u03 = A[(size_t)nd[0] * n + nd[3]];
            u13 = A[(size_t)nd[1] * n + nd[3]];
            u23 = A[(size_t)nd[2] * n + nd[3]];
            d33 = 0.0f;
        }
        float M[4][4] = {{0.0f, u01, u02, u03},
                         {u01, 0.0f, u12, u13},
                         {u02, u12, 0.0f, u23},
                         {u03, u13, u23, d33}};
#pragma unroll
        for (int a = 0; a < 4; a++) {
            float rs = M[a][0] + M[a][1] + M[a][2] + M[a][3];
            rs = fmaxf(rs, 1e-12f);
            float inv = 1.0f / rs;
#pragma unroll
            for (int b = 0; b < 4; b++) M[a][b] *= inv;
        }
        float t1 = M[0][0] + M[1][1] + M[2][2] + M[3][3];
        float t2 = 0, t3 = 0;
#pragma unroll
        for (int a = 0; a < 4; a++)
#pragma unroll
            for (int b = 0; b < 4; b++) {
                float ab = M[a][b];
                t2 += ab * M[b][a];
                float a3 = 0;
#pragma unroll
                for (int c = 0; c < 4; c++) a3 += M[b][c] * M[c][a];
                t3 += ab * a3;
            }
        if (isTri) { t1 -= 1.0f; t2 -= 1.0f; t3 -= 1.0f; }

#pragma unroll
        for (int L = 0; L < 2; L++) {
            float sims[8], mx = -1e30f;
#pragma unroll
            for (int f = 0; f < 8; f++) {
                sims[f] = dcs[m][L][f][0] * t1 + dcs[m][L][f][1] * t2 +
                          dcs[m][L][f][2] * t3;
                mx = fmaxf(mx, sims[f]);
            }
            float es[8], se = 0;
#pragma unroll
            for (int f = 0; f < 8; f++) { es[f] = expf(sims[f] - mx); se += es[f]; }
            float si = 1.0f / se;
            f32x4 c0, c1;
#pragma unroll
            for (int f = 0; f < 4; f++) c0[f] = es[f] * si * sims[f] * kinv;
#pragma unroll
            for (int f = 0; f < 4; f++) c1[f] = es[f + 4] * si * sims[f + 4] * kinv;
            float* cp = cont + ((size_t)L * Itot + gi) * 8;
            *(f32x4*)cp = c0;
            *(f32x4*)(cp + 4) = c1;
        }

        // push gi into each DISTINCT tile touched (dedupe; expansion re-reads nodes)
#pragma unroll
        for (int j = 0; j < 4; j++) {
            if (j >= K) break;
            int t = nd[j] >> 4;
            bool dup = false;
#pragma unroll
            for (int jj = 0; jj < 3; jj++)
                if (jj < j) dup |= ((nd[jj] >> 4) == t);
            if (!dup) {
                int pos = atomicAdd(&tcnt[t], 1);
                if (pos < TCAP) bucket[(size_t)t * TCAP + pos] = gi;
            }
        }
    } else if (bid < BC + n) {
        __shared__ float red[4];
        int row = bid - BC;
        const float4* Arow = (const float4*)(A + (size_t)row * n);
        int n4 = n >> 2;
        float s = 0.0f;
        for (int i = tid; i < n4; i += 256) {
            float4 v = Arow[i];
            s += v.x + v.y + v.z + v.w;
        }
        for (int off = 32; off > 0; off >>= 1) s += __shfl_down(s, off);
        if ((tid & 63) == 0) red[tid >> 6] = s;
        __syncthreads();
        if (tid == 0) {
            float t = red[0] + red[1] + red[2] + red[3];
            H0[row] = t;
            out[(size_t)row * 257 + 256] = t;
        }
    }
}

// ===========================================================================
// K2 (512 thr, one 16-row tile per block): read tile bucket -> expand to
// per-row LDS queues (occurrence-accurate) -> half-wave drain -> LN/MFMA tail
// ===========================================================================
__global__ __launch_bounds__(512) void k2_kernel(
    const int* __restrict__ tri, const int* __restrict__ cyc,
    const float* __restrict__ cont, const int* __restrict__ tcnt,
    const int* __restrict__ bucket, const float* __restrict__ H0,
    const float* __restrict__ lng0, const float* __restrict__ lnb0,
    const uint16_t* __restrict__ Wb10, const float* __restrict__ b1_0,
    const uint16_t* __restrict__ Wb20, const float* __restrict__ b2_0,
    const float* __restrict__ lng1, const float* __restrict__ lnb1,
    const uint16_t* __restrict__ Wb11, const float* __restrict__ b1_1,
    const uint16_t* __restrict__ Wb21, const float* __restrict__ b2_1,
    float* __restrict__ out, int n, int Itri, int Icyc) {

    // row queues (expand/drain) overlay Xs/Hs/Zs (tail) -- disjoint lifetimes
    __shared__ __align__(16) char upool[18432];
    int* rowq = (int*)upool;                                  // 16*RQCAP = 6144 B
    uint16_t (*Xs)[168] = (uint16_t(*)[168])upool;            // 5376 B
    uint16_t (*Hs)[136] = (uint16_t(*)[136])(upool + 5376);   // 4352 B
    float    (*Zs)[132] = (float(*)[132])(upool + 9728);      // 8448 B
    __shared__ float phi[2][2][16][8];   // [L][m][r][f]
    __shared__ float h0s[16];
    __shared__ int rowcnt[16];

    const int tid  = threadIdx.x;
    const int tile = blockIdx.x;
    const int v0   = tile * 16;
    const int lane = tid & 63;
    const int Itot = Itri + Icyc;

    if (tid < 16) { rowcnt[tid] = 0; h0s[tid] = H0[v0 + tid]; }
    __syncthreads();

    // ---- expand: bucket entries -> per-row queues (per occurrence) ----
    {
        int cnt = tcnt[tile]; cnt = cnt < TCAP ? cnt : TCAP;
        for (int e = tid; e < cnt; e += 512) {
            int gi = bucket[(size_t)tile * TCAP + e];
            bool isTri = gi < Itri;
            int K = isTri ? 3 : 4;
            const int* p = isTri ? tri + gi * 3 : cyc + (size_t)(gi - Itri) * 4;
#pragma unroll
            for (int j = 0; j < 4; j++) {
                if (j >= K) break;
                unsigned r = (unsigned)(p[j] - v0);
                if (r < 16u) {
                    int pos = atomicAdd(&rowcnt[r], 1);
                    if (pos < RQCAP) rowq[r * RQCAP + pos] = gi;
                }
            }
        }
    }
    __syncthreads();

    // ---- drain: half-wave per row; lanes = (sub, L, f); no atomics ----
    {
        int r = tid >> 5;
        int l32 = tid & 31;
        int sub = l32 >> 4;
        int c = l32 & 15;
        int f = c & 7, L = c >> 3;
        int cnt = rowcnt[r]; cnt = cnt < RQCAP ? cnt : RQCAP;
        float acc0 = 0.0f, acc1 = 0.0f;
        for (int qi = sub; qi < cnt; qi += 2) {
            int gi = rowq[r * RQCAP + qi];
            float v = cont[((size_t)L * Itot + gi) * 8 + f];
            if (gi >= Itri) acc1 += v; else acc0 += v;
        }
        acc0 += __shfl_xor(acc0, 16);
        acc1 += __shfl_xor(acc1, 16);
        if (sub == 0) {
            phi[L][0][r][f] = acc0;
            phi[L][1][r][f] = acc1;
        }
    }
    __syncthreads();

    // ---- LN0 -> Xs[:,0..31] ----
    {
        int r = tid >> 5;
        int j = tid & 31;
        float x = (j < 16) ? phi[0][j >> 3][r][j & 7] : (j == 16 ? h0s[r] : 0.0f);
        float s1 = x, s2 = x * x;
        for (int o = 16; o > 0; o >>= 1) { s1 += __shfl_xor(s1, o); s2 += __shfl_xor(s2, o); }
        float mu = s1 / 17.0f;
        float rstd = rsqrtf(s2 / 17.0f - mu * mu + 1e-5f);
        Xs[r][j] = (j < 17) ? f2bf((x - mu) * rstd * lng0[j] + lnb0[j]) : (uint16_t)0;
    }
    __syncthreads();

    // ---- G1 layer0 (K=32) ----
    {
        int w8 = tid >> 6, lr = lane & 15, lg = lane >> 4;
        int col = w8 * 16 + lr;
        f32x4 acc = {0.f, 0.f, 0.f, 0.f};
        short8v a = *(const short8v*)&Xs[lr][lg * 8];
        short8v b = *(const short8v*)(Wb10 + (size_t)col * 32 + lg * 8);
        acc = __builtin_amdgcn_mfma_f32_16x16x32_bf16(a, b, acc, 0, 0, 0);
        float bias = b1_0[col];
#pragma unroll
        for (int i = 0; i < 4; i++)
            Hs[lg * 4 + i][col] = f2bf(gelu_exact(acc[i] + bias));
    }
    __syncthreads();

    // ---- G2 layer0 -> out[:,128..255] + Zs ----
    {
        int w8 = tid >> 6, lr = lane & 15, lg = lane >> 4;
        int col = w8 * 16 + lr;
        f32x4 acc = {0.f, 0.f, 0.f, 0.f};
#pragma unroll
        for (int ks = 0; ks < 4; ks++) {
            short8v a = *(const short8v*)&Hs[lr][ks * 32 + lg * 8];
            short8v b = *(const short8v*)(Wb20 + (size_t)col * 128 + ks * 32 + lg * 8);
            acc = __builtin_amdgcn_mfma_f32_16x16x32_bf16(a, b, acc, 0, 0, 0);
        }
        float bias = b2_0[col];
#pragma unroll
        for (int i = 0; i < 4; i++) {
            int row = lg * 4 + i;
            float val = acc[i] + bias;
            out[(size_t)(v0 + row) * 257 + 128 + col] = val;
            Zs[row][col] = val;
        }
    }
    __syncthreads();

    // ---- LN1 -> Xs[:,0..159] ----
    {
        int rr = tid >> 5;
        int t = tid & 31;
        float ph[5];
        float s1 = 0.0f, s2 = 0.0f;
#pragma unroll
        for (int s = 0; s < 5; s++) {
            int j = t + 32 * s;
            float x = 0.0f;
            if (j < 16) x = phi[1][j >> 3][rr][j & 7];
            else if (j < 144) x = Zs[rr][j - 16];
            else if (j == 144) x = h0s[rr];
            ph[s] = x;
            if (j < 145) { s1 += x; s2 += x * x; }
        }
        for (int o = 16; o > 0; o >>= 1) { s1 += __shfl_xor(s1, o); s2 += __shfl_xor(s2, o); }
        float mu = s1 / 145.0f;
        float rstd = rsqrtf(s2 / 145.0f - mu * mu + 1e-5f);
#pragma unroll
        for (int s = 0; s < 5; s++) {
            int j = t + 32 * s;
            Xs[rr][j] = (j < 145) ? f2bf((ph[s] - mu) * rstd * lng1[j] + lnb1[j])
                                  : (uint16_t)0;
        }
    }
    __syncthreads();

    // ---- G1 layer1 (K=160) ----
    {
        int w8 = tid >> 6, lr = lane & 15, lg = lane >> 4;
        int col = w8 * 16 + lr;
        f32x4 acc = {0.f, 0.f, 0.f, 0.f};
#pragma unroll
        for (int ks = 0; ks < 5; ks++) {
            short8v a = *(const short8v*)&Xs[lr][ks * 32 + lg * 8];
            short8v b = *(const short8v*)(Wb11 + (size_t)col * 160 + ks * 32 + lg * 8);
            acc = __builtin_amdgcn_mfma_f32_16x16x32_bf16(a, b, acc, 0, 0, 0);
        }
        float bias = b1_1[col];
#pragma unroll
        for (int i = 0; i < 4; i++)
            Hs[lg * 4 + i][col] = f2bf(gelu_exact(acc[i] + bias));
    }
    __syncthreads();

    // ---- G2 layer1 -> out[:,0..127] ----
    {
        int w8 = tid >> 6, lr = lane & 15, lg = lane >> 4;
        int col = w8 * 16 + lr;
        f32x4 acc = {0.f, 0.f, 0.f, 0.f};
#pragma unroll
        for (int ks = 0; ks < 4; ks++) {
            short8v a = *(const short8v*)&Hs[lr][ks * 32 + lg * 8];
            short8v b = *(const short8v*)(Wb21 + (size_t)col * 128 + ks * 32 + lg * 8);
            acc = __builtin_amdgcn_mfma_f32_16x16x32_bf16(a, b, acc, 0, 0, 0);
        }
        float bias = b2_1[col];
#pragma unroll
        for (int i = 0; i < 4; i++) {
            int row = lg * 4 + i;
            out[(size_t)(v0 + row) * 257 + col] = acc[i] + bias;
        }
    }
}

extern "C" void kernel_launch(void* const* d_in, const int* in_sizes, int n_in,
                              void* d_out, int out_size, void* d_ws, size_t ws_size,
                              hipStream_t stream) {
    const float* A    = (const float*)d_in[0];
    const int*   tri  = (const int*)d_in[1];
    const int*   cyc  = (const int*)d_in[2];

    int n    = out_size / 257;          // 4096
    int Itri = in_sizes[1] / 3;         // 30000
    int Icyc = in_sizes[2] / 4;         // 15000
    int Itot = Itri + Icyc;
    int ntiles = n / 16;                // 256

    float* ws = (float*)d_ws;
    float* dcoef = ws;                                   // 128
    float* H0    = ws + 128;                             // n
    float* cont  = H0 + n;                               // 2*Itot*8
    int* tcnt    = (int*)(cont + (size_t)2 * Itot * 8);  // ntiles
    int* bucket  = tcnt + 256;                           // ntiles*TCAP
    uint16_t* Wb10 = (uint16_t*)(bucket + (size_t)ntiles * TCAP);
    uint16_t* Wb20 = Wb10 + 128 * 32;
    uint16_t* Wb11 = Wb20 + 128 * 128;
    uint16_t* Wb21 = Wb11 + 128 * 160;
    float* out = (float*)d_out;

    k0_kernel<<<64, 256, 0, stream>>>(
        (const float*)d_in[3], (const float*)d_in[4], (const float*)d_in[5],
        (const float*)d_in[12], (const float*)d_in[13], (const float*)d_in[14],
        (const float*)d_in[8], (const float*)d_in[10],
        (const float*)d_in[17], (const float*)d_in[19],
        dcoef, tcnt, Wb10, Wb20, Wb11, Wb21, ntiles);

    int BC = (Itot + 255) / 256;   // 176 contrib blocks
    k1_kernel<<<BC + n, 256, 0, stream>>>(
        A, tri, cyc, dcoef, cont, tcnt, bucket, H0, out, n, Itri, Icyc, BC);

    k2_kernel<<<ntiles, 512, 0, stream>>>(
        tri, cyc, cont, tcnt, bucket, H0,
        (const float*)d_in[6], (const float*)d_in[7],
        Wb10, (const float*)d_in[9], Wb20, (const float*)d_in[11],
        (const float*)d_in[15], (const float*)d_in[16],
        Wb11, (const float*)d_in[18], Wb21, (const float*)d_in[20],
        out, n, Itri, Icyc);
}

// Round 13
// 78.788 us; speedup vs baseline: 1.5459x; 1.5459x over previous
//
#include <hip/hip_runtime.h>
#include <math.h>
#include <stdint.h>

#define GAMMA 0.7f
#define CAP 96

typedef __attribute__((ext_vector_type(8))) short short8v;   // 8 bf16
typedef __attribute__((ext_vector_type(4))) float f32x4;

__device__ __forceinline__ float sp_dev(float x) {
    return fmaxf(x, 0.0f) + log1pf(expf(-fabsf(x)));
}
__device__ __forceinline__ float gelu_exact(float x) {
    return 0.5f * x * (1.0f + erff(x * 0.70710678118654752f));
}
__device__ __forceinline__ uint16_t f2bf(float x) {
    union { float f; uint32_t u; } c; c.f = x;
    uint32_t u = c.u + 0x7FFFu + ((c.u >> 16) & 1u);
    return (uint16_t)(u >> 16);
}

// walk coefficients for one (layer,filter) of one motif
__device__ __forceinline__ void walk_coef(const float* __restrict__ W,
                                          const float* __restrict__ g,
                                          int f, int k, float* d) {
    float S[4][4], Y[4][4];
    for (int a = 0; a < k; a++)
        for (int b = 0; b < k; b++)
            S[a][b] = sp_dev(W[(f * k + a) * k + b]);
    for (int a = 0; a < k; a++)
        for (int b = 0; b < k; b++)
            Y[a][b] = (a == b) ? 0.0f : 0.5f * (S[a][b] + S[b][a]);
    for (int a = 0; a < k; a++) {
        float rs = 0.0f;
        for (int b = 0; b < k; b++) rs += Y[a][b];
        rs = fmaxf(rs, 1e-12f);
        for (int b = 0; b < k; b++) Y[a][b] /= rs;
    }
    float t1 = 0, t2 = 0, t3 = 0;
    for (int a = 0; a < k; a++) t1 += Y[a][a];
    for (int a = 0; a < k; a++)
        for (int b = 0; b < k; b++) t2 += Y[a][b] * Y[b][a];
    for (int a = 0; a < k; a++)
        for (int b = 0; b < k; b++)
            for (int c = 0; c < k; c++) t3 += Y[a][b] * Y[b][c] * Y[c][a];
    d[0] = GAMMA * sp_dev(g[0]) * t1;
    d[1] = GAMMA * GAMMA * sp_dev(g[1]) * t2;
    d[2] = GAMMA * GAMMA * GAMMA * sp_dev(g[2]) * t3;
}

// ===========================================================================
// K0: zero cursor (tiny)
// ===========================================================================
__global__ void k0_zero(int* __restrict__ cursor, int ncur) {
    int i = blockIdx.x * 256 + threadIdx.x;
    int stride = gridDim.x * 256;
    for (; i < ncur; i += stride) cursor[i] = 0;
}

// ===========================================================================
// contrib: 4 lanes per instance; SYMMETRIC loads (3 tri / 6 cyc off-diag),
// broadcast by shuffles; padded 4x4 (tri row3=[0,0,0,1], traces -1).
// Writes dense cont (per-motif array) + cursor/slotbuf inverted index.
// ===========================================================================
template <int K>
__device__ __forceinline__ void contrib4(
    const float* __restrict__ A, int n, const int* __restrict__ idx,
    int li, int lane, const float (*dc)[8][3],
    float* __restrict__ cont, int I,
    int* __restrict__ cursor, int* __restrict__ slotbuf) {
    int g = lane & 3;
    int base = lane & ~3;
    int mynode = (g < K) ? idx[li * K + g] : 0;
    int nb0 = __shfl(mynode, base + 0);
    int nb1 = __shfl(mynode, base + 1);
    int nb2 = __shfl(mynode, base + 2);
    int nb3 = (K == 4) ? __shfl(mynode, base + 3) : 0;

    // symmetric off-diagonal loads, 1-2 per lane
    float va = 0.0f, vb = 0.0f;
    if (K == 4) {
        if (g == 0)      { va = A[(size_t)nb0 * n + nb1]; vb = A[(size_t)nb0 * n + nb3]; }
        else if (g == 1) { va = A[(size_t)nb1 * n + nb2]; vb = A[(size_t)nb1 * n + nb3]; }
        else if (g == 2) { va = A[(size_t)nb2 * n + nb3]; }
        else             { va = A[(size_t)nb0 * n + nb2]; }
    } else {
        if (g == 0)      va = A[(size_t)nb0 * n + nb1];
        else if (g == 1) va = A[(size_t)nb1 * n + nb2];
        else if (g == 3) va = A[(size_t)nb0 * n + nb2];
    }
    float u01 = __shfl(va, base + 0);
    float u12 = __shfl(va, base + 1);
    float u02 = __shfl(va, base + 3);
    float u03 = 0.0f, u13 = 0.0f, u23 = 0.0f, d33 = 1.0f;
    if (K == 4) {
        u03 = __shfl(vb, base + 0);
        u13 = __shfl(vb, base + 1);
        u23 = __shfl(va, base + 2);
        d33 = 0.0f;
    }

    float M[4][4] = {{0.0f, u01, u02, u03},
                     {u01, 0.0f, u12, u13},
                     {u02, u12, 0.0f, u23},
                     {u03, u13, u23, d33}};
#pragma unroll
    for (int a = 0; a < 4; a++) {
        float rs = fmaxf(M[a][0] + M[a][1] + M[a][2] + M[a][3], 1e-12f);
        float inv = 1.0f / rs;
#pragma unroll
        for (int b = 0; b < 4; b++) M[a][b] *= inv;
    }
    float t1 = M[0][0] + M[1][1] + M[2][2] + M[3][3];
    float t2 = 0.0f, t3 = 0.0f;
#pragma unroll
    for (int a = 0; a < 4; a++)
#pragma unroll
        for (int b = 0; b < 4; b++) {
            float ab = M[a][b];
            t2 += ab * M[b][a];
            float a3 = 0.0f;
#pragma unroll
            for (int c = 0; c < 4; c++) a3 += M[b][c] * M[c][a];
            t3 += ab * a3;
        }
    if (K == 3) { t1 -= 1.0f; t2 -= 1.0f; t3 -= 1.0f; }

    const float kinv = 1.0f / (float)K;
#pragma unroll
    for (int L = 0; L < 2; L++) {
        float sims[8], mx = -1e30f;
#pragma unroll
        for (int f = 0; f < 8; f++) {
            sims[f] = dc[L][f][0] * t1 + dc[L][f][1] * t2 + dc[L][f][2] * t3;
            mx = fmaxf(mx, sims[f]);
        }
        float es[8], se = 0.0f;
#pragma unroll
        for (int f = 0; f < 8; f++) { es[f] = expf(sims[f] - mx); se += es[f]; }
        float sinv = 1.0f / se;
        float cn[8];
#pragma unroll
        for (int f = 0; f < 8; f++) cn[f] = es[f] * sinv * sims[f] * kinv;
        float p0 = (g == 0) ? cn[0] : (g == 1) ? cn[2] : (g == 2) ? cn[4] : cn[6];
        float p1 = (g == 0) ? cn[1] : (g == 1) ? cn[3] : (g == 2) ? cn[5] : cn[7];
        *(float2*)(cont + ((size_t)L * I + li) * 8 + 2 * g) = make_float2(p0, p1);
    }

    if (g < K) {
        int pos = atomicAdd(&cursor[mynode], 1);
        if (pos < CAP) slotbuf[(size_t)mynode * CAP + pos] = li;
    }
}

// ===========================================================================
// fused: [0,BT) tri contrib ; [BT,BT+BCY) cyc contrib ; [.., +n) rowsum ;
// [.., +BP) bf16 transposed weights (needed only by mega).
// ===========================================================================
__global__ __launch_bounds__(256) void fused_kernel(
    const float* __restrict__ A, const int* __restrict__ tri, const int* __restrict__ cyc,
    const float* __restrict__ Wt0, const float* __restrict__ Wc0, const float* __restrict__ g0,
    const float* __restrict__ Wt1, const float* __restrict__ Wc1, const float* __restrict__ g1,
    const float* __restrict__ w1_0, const float* __restrict__ w2_0,
    const float* __restrict__ w1_1, const float* __restrict__ w2_1,
    float* __restrict__ tri_c, float* __restrict__ cyc_c,
    int* __restrict__ cursor, int* __restrict__ slotbuf,
    float* __restrict__ H0,
    uint16_t* __restrict__ Wb10, uint16_t* __restrict__ Wb20,
    uint16_t* __restrict__ Wb11, uint16_t* __restrict__ Wb21,
    float* __restrict__ out, int n, int Itri, int Icyc, int BT, int BCY) {

    const int tid = threadIdx.x;
    const int bid = blockIdx.x;
    const int lane = tid & 63;

    if (bid < BT + BCY) {
        bool isTri = bid < BT;
        __shared__ float dc[2][8][3];
        if (tid < 16) {
            int L = tid >> 3, f = tid & 7;
            const float* W = isTri ? (L ? Wt1 : Wt0) : (L ? Wc1 : Wc0);
            const float* g = L ? g1 : g0;
            walk_coef(W, g, f, isTri ? 3 : 4, &dc[L][f][0]);
        }
        __syncthreads();
        if (isTri) {
            int li = bid * 64 + (tid >> 2);
            if (li < Itri)
                contrib4<3>(A, n, tri, li, lane, dc, tri_c, Itri, cursor, slotbuf);
        } else {
            int li = (bid - BT) * 64 + (tid >> 2);
            if (li < Icyc)
                contrib4<4>(A, n, cyc, li, lane, dc, cyc_c, Icyc,
                            cursor + n, slotbuf + (size_t)n * CAP);
        }
    } else if (bid < BT + BCY + n) {
        __shared__ float red[4];
        int row = bid - BT - BCY;
        const float4* Arow = (const float4*)(A + (size_t)row * n);
        int n4 = n >> 2;
        float s = 0.0f;
        for (int i = tid; i < n4; i += 256) {
            float4 v = Arow[i];
            s += v.x + v.y + v.z + v.w;
        }
        for (int off = 32; off > 0; off >>= 1) s += __shfl_down(s, off);
        if ((tid & 63) == 0) red[tid >> 6] = s;
        __syncthreads();
        if (tid == 0) {
            float t = red[0] + red[1] + red[2] + red[3];
            H0[row] = t;
            out[(size_t)row * 257 + 256] = t;
        }
    } else {
        int base = (bid - BT - BCY - n) * 4096;
        for (int k = 0; k < 16; k++) {
            int idx = base + k * 256 + tid;
            if (idx >= 57344) break;
            if (idx < 4096) {
                int c = idx >> 5, kk = idx & 31;
                Wb10[idx] = (kk < 17) ? f2bf(w1_0[kk * 128 + c]) : 0;
            } else if (idx < 20480) {
                int e = idx - 4096; int c = e >> 7, kk = e & 127;
                Wb20[e] = f2bf(w2_0[kk * 128 + c]);
            } else if (idx < 40960) {
                int e = idx - 20480; int c = e / 160, kk = e % 160;
                Wb11[e] = (kk < 145) ? f2bf(w1_1[kk * 128 + c]) : 0;
            } else {
                int e = idx - 40960; int c = e >> 7, kk = e & 127;
                Wb21[e] = f2bf(w2_1[kk * 128 + c]);
            }
        }
    }
}

// ===========================================================================
// mega (R5-proven): per 16-node tile: slotbuf gather -> LN0 -> G1_0 -> G2_0
// (out cols 128..255) -> LN1 -> G1_1 -> G2_1 (out cols 0..127). 512 threads.
// ===========================================================================
__global__ __launch_bounds__(512) void mega_kernel(
    const float* __restrict__ tri_c, int Itri,
    const float* __restrict__ cyc_c, int Icyc,
    const int* __restrict__ cursor, const int* __restrict__ slotbuf,
    const float* __restrict__ H0,
    const float* __restrict__ lng0, const float* __restrict__ lnb0,
    const uint16_t* __restrict__ Wb10, const float* __restrict__ b1_0,
    const uint16_t* __restrict__ Wb20, const float* __restrict__ b2_0,
    const float* __restrict__ lng1, const float* __restrict__ lnb1,
    const uint16_t* __restrict__ Wb11, const float* __restrict__ b1_1,
    const uint16_t* __restrict__ Wb21, const float* __restrict__ b2_1,
    float* __restrict__ out, int n) {
    __shared__ uint16_t Xs[16][168];
    __shared__ uint16_t Hs[16][136];
    __shared__ float    Zs[16][129];
    __shared__ float    phi0[16][17];
    __shared__ float    f1[16][16];
    __shared__ float    h0s[16];

    int tid = threadIdx.x;
    int v0 = blockIdx.x * 16;
    int wave = tid >> 6;
    int lane = tid & 63;
    int lr = lane & 15, lg = lane >> 4;

    // ---- gather: thread = (node r, combo{m,L,f}) ----
    {
        int r = tid >> 5;
        int combo = tid & 31;
        int m = combo >> 4, L = (combo >> 3) & 1, f = combo & 7;
        int v = v0 + r;
        int cnt = cursor[m * n + v];
        cnt = cnt < CAP ? cnt : CAP;
        const int* bucket = slotbuf + ((size_t)(m * n + v)) * CAP;
        const float* c = m ? cyc_c : tri_c;
        int I = m ? Icyc : Itri;
        float sum = 0.0f;
        for (int j = 0; j < cnt; j++) {
            int i = bucket[j];
            sum += c[((size_t)L * I + i) * 8 + f];
        }
        if (L == 0) phi0[r][m * 8 + f] = sum;
        else        f1[r][m * 8 + f] = sum;
        if (combo == 0) { float h = H0[v]; phi0[r][16] = h; h0s[r] = h; }
    }
    __syncthreads();

    // ---- LN0 -> Xs[:,0..31] ----
    {
        int r = tid >> 5;
        int j = tid & 31;
        float x = (j < 17) ? phi0[r][j] : 0.0f;
        float s1 = x, s2 = x * x;
        for (int o = 16; o > 0; o >>= 1) { s1 += __shfl_xor(s1, o); s2 += __shfl_xor(s2, o); }
        float mu = s1 / 17.0f;
        float rstd = rsqrtf(s2 / 17.0f - mu * mu + 1e-5f);
        Xs[r][j] = (j < 17) ? f2bf((x - mu) * rstd * lng0[j] + lnb0[j]) : (uint16_t)0;
    }
    __syncthreads();

    // ---- G1 layer0 (K=32) ----
    {
        int col = wave * 16 + lr;
        f32x4 acc = {0.f, 0.f, 0.f, 0.f};
        short8v a = *(const short8v*)&Xs[lr][lg * 8];
        short8v b = *(const short8v*)(Wb10 + (size_t)col * 32 + lg * 8);
        acc = __builtin_amdgcn_mfma_f32_16x16x32_bf16(a, b, acc, 0, 0, 0);
        float bias = b1_0[col];
#pragma unroll
        for (int i = 0; i < 4; i++)
            Hs[lg * 4 + i][col] = f2bf(gelu_exact(acc[i] + bias));
    }
    __syncthreads();

    // ---- G2 layer0 -> out[:,128..255] + Zs ----
    {
        int col = wave * 16 + lr;
        f32x4 acc = {0.f, 0.f, 0.f, 0.f};
#pragma unroll
        for (int ks = 0; ks < 4; ks++) {
            short8v a = *(const short8v*)&Hs[lr][ks * 32 + lg * 8];
            short8v b = *(const short8v*)(Wb20 + (size_t)col * 128 + ks * 32 + lg * 8);
            acc = __builtin_amdgcn_mfma_f32_16x16x32_bf16(a, b, acc, 0, 0, 0);
        }
        float bias = b2_0[col];
#pragma unroll
        for (int i = 0; i < 4; i++) {
            int row = lg * 4 + i;
            float val = acc[i] + bias;
            out[(size_t)(v0 + row) * 257 + 128 + col] = val;
            Zs[row][col] = val;
        }
    }
    __syncthreads();

    // ---- LN1: phi[145] = [f1(16), Zs(128), H0] -> Xs[:,0..159] ----
    {
        int rr = tid >> 5;
        int t = tid & 31;
        float ph[5];
        float s1 = 0.0f, s2 = 0.0f;
#pragma unroll
        for (int s = 0; s < 5; s++) {
            int j = t + 32 * s;
            float x = 0.0f;
            if (j < 16) x = f1[rr][j];
            else if (j < 144) x = Zs[rr][j - 16];
            else if (j == 144) x = h0s[rr];
            ph[s] = x;
            if (j < 145) { s1 += x; s2 += x * x; }
        }
        for (int o = 16; o > 0; o >>= 1) { s1 += __shfl_xor(s1, o); s2 += __shfl_xor(s2, o); }
        float mu = s1 / 145.0f;
        float rstd = rsqrtf(s2 / 145.0f - mu * mu + 1e-5f);
#pragma unroll
        for (int s = 0; s < 5; s++) {
            int j = t + 32 * s;
            Xs[rr][j] = (j < 145) ? f2bf((ph[s] - mu) * rstd * lng1[j] + lnb1[j]) : (uint16_t)0;
        }
    }
    __syncthreads();

    // ---- G1 layer1 (K=160) ----
    {
        int col = wave * 16 + lr;
        f32x4 acc = {0.f, 0.f, 0.f, 0.f};
#pragma unroll
        for (int ks = 0; ks < 5; ks++) {
            short8v a = *(const short8v*)&Xs[lr][ks * 32 + lg * 8];
            short8v b = *(const short8v*)(Wb11 + (size_t)col * 160 + ks * 32 + lg * 8);
            acc = __builtin_amdgcn_mfma_f32_16x16x32_bf16(a, b, acc, 0, 0, 0);
        }
        float bias = b1_1[col];
#pragma unroll
        for (int i = 0; i < 4; i++)
            Hs[lg * 4 + i][col] = f2bf(gelu_exact(acc[i] + bias));
    }
    __syncthreads();

    // ---- G2 layer1 -> out[:,0..127] ----
    {
        int col = wave * 16 + lr;
        f32x4 acc = {0.f, 0.f, 0.f, 0.f};
#pragma unroll
        for (int ks = 0; ks < 4; ks++) {
            short8v a = *(const short8v*)&Hs[lr][ks * 32 + lg * 8];
            short8v b = *(const short8v*)(Wb21 + (size_t)col * 128 + ks * 32 + lg * 8);
            acc = __builtin_amdgcn_mfma_f32_16x16x32_bf16(a, b, acc, 0, 0, 0);
        }
        float bias = b2_1[col];
#pragma unroll
        for (int i = 0; i < 4; i++) {
            int row = lg * 4 + i;
            out[(size_t)(v0 + row) * 257 + col] = acc[i] + bias;
        }
    }
}

extern "C" void kernel_launch(void* const* d_in, const int* in_sizes, int n_in,
                              void* d_out, int out_size, void* d_ws, size_t ws_size,
                              hipStream_t stream) {
    const float* A    = (const float*)d_in[0];
    const int*   tri  = (const int*)d_in[1];
    const int*   cyc  = (const int*)d_in[2];

    int n    = out_size / 257;          // 4096
    int Itri = in_sizes[1] / 3;         // 30000
    int Icyc = in_sizes[2] / 4;         // 15000

    float* ws    = (float*)d_ws;
    float* H0    = ws;                                   // n
    float* tri_c = H0 + n;                               // 2*Itri*8
    float* cyc_c = tri_c + (size_t)2 * Itri * 8;         // 2*Icyc*8
    int*   cursor  = (int*)(cyc_c + (size_t)2 * Icyc * 8);   // 2n
    int*   slotbuf = cursor + (size_t)2 * n;                 // 2n*CAP
    uint16_t* Wb10 = (uint16_t*)(slotbuf + (size_t)2 * n * CAP); // 128*32
    uint16_t* Wb20 = Wb10 + 128 * 32;                    // 128*128
    uint16_t* Wb11 = Wb20 + 128 * 128;                   // 128*160
    uint16_t* Wb21 = Wb11 + 128 * 160;                   // 128*128
    float* out = (float*)d_out;

    k0_zero<<<8, 256, 0, stream>>>(cursor, 2 * n);

    int BT  = (Itri + 63) / 64;      // 469
    int BCY = (Icyc + 63) / 64;      // 235
    int BP  = 14;                    // weight-transpose blocks
    fused_kernel<<<BT + BCY + n + BP, 256, 0, stream>>>(
        A, tri, cyc,
        (const float*)d_in[3], (const float*)d_in[4], (const float*)d_in[5],
        (const float*)d_in[12], (const float*)d_in[13], (const float*)d_in[14],
        (const float*)d_in[8], (const float*)d_in[10],
        (const float*)d_in[17], (const float*)d_in[19],
        tri_c, cyc_c, cursor, slotbuf, H0,
        Wb10, Wb20, Wb11, Wb21, out, n, Itri, Icyc, BT, BCY);

    mega_kernel<<<n / 16, 512, 0, stream>>>(
        tri_c, Itri, cyc_c, Icyc, cursor, slotbuf, H0,
        (const float*)d_in[6], (const float*)d_in[7],
        Wb10, (const float*)d_in[9], Wb20, (const float*)d_in[11],
        (const float*)d_in[15], (const float*)d_in[16],
        Wb11, (const float*)d_in[18], Wb21, (const float*)d_in[20],
        out, n);
}